// Round 4
// baseline (368.902 us; speedup 1.0000x reference)
//
#include <hip/hip_runtime.h>
#include <hip/hip_bf16.h>

#define N_ROWS 4096
#define K_IN   8192
#define F_DIM  2048
#define GAMMA  (1.0f / 2048.0f)

typedef unsigned short u16;
typedef unsigned int   u32;
typedef unsigned char  u8;
typedef __attribute__((ext_vector_type(4))) int   i32x4;
typedef __attribute__((ext_vector_type(8))) int   i32x8;
typedef __attribute__((ext_vector_type(4))) float f32x4;
typedef __attribute__((ext_vector_type(2))) float f32x2;

// pack 4 floats -> 4 fp8 e4m3 bytes (hw RNE conversion)
__device__ __forceinline__ u32 pk4_fp8(float a, float b, float c, float d) {
  u32 u = 0;
  u = __builtin_amdgcn_cvt_pk_fp8_f32(a, b, u, false);
  u = __builtin_amdgcn_cvt_pk_fp8_f32(c, d, u, true);
  return u;
}
__device__ __forceinline__ u8 f8(float v) {
  return (u8)(__builtin_amdgcn_cvt_pk_fp8_f32(v, v, 0, false) & 0xff);
}
__device__ __forceinline__ float f8_dec(u8 b) {
  f32x2 d = __builtin_amdgcn_cvt_pk_f32_fp8((u32)b, false);
  return d[0];
}

__device__ __forceinline__ void async16(const void* g, void* l) {
  __builtin_amdgcn_global_load_lds(
      (const __attribute__((address_space(1))) void*)g,
      (__attribute__((address_space(3))) void*)l, 16, 0, 0);
}

// ---------------- fused prep: convert xs + transpose W + beta/sq init ---------
// blocks [0, 8192):       xs fp32 -> fp8 e4m3 (unit scale, N(0,1) fits)
// blocks [8192, 12288):   W [K_IN,F_DIM] fp32 -> Wt [F_DIM,K_IN] fp8 x64
//                         (w~0.011 is subnormal in e4m3; 2^-6 folded back via
//                          the MFMA B-scale operand)
// block 12288:            beta = alpha*(2y-1); out[0] = -sum(alpha); sq = 0
__global__ __launch_bounds__(256) void fused_prep(
    const float4* __restrict__ xs4, u32* __restrict__ xs_f8,
    const float* __restrict__ W, u8* __restrict__ Wt,
    const float* __restrict__ alphas, const int* __restrict__ ys,
    float* __restrict__ beta, float* __restrict__ sq, float* __restrict__ out) {
  __shared__ float tile[128][33];
  __shared__ float red[256];
  const int bid = blockIdx.x;
  const int tid = threadIdx.x;

  if (bid < 8192) {                       // ---- convert xs
    int base = bid * 1024 + tid;
#pragma unroll
    for (int k = 0; k < 4; ++k) {
      int i = base + k * 256;
      float4 v = xs4[i];
      xs_f8[i] = pk4_fp8(v.x, v.y, v.z, v.w);
    }
  } else if (bid < 12288) {               // ---- transpose + convert W
    int t = bid - 8192;
    int k0 = (t & 63) * 128;              // K chunk
    int f0 = (t >> 6) * 32;               // F chunk
    int tx = tid & 31, ty = tid >> 5;     // (32, 8)
#pragma unroll
    for (int kk = 0; kk < 16; ++kk) {
      int k = kk * 8 + ty;
      tile[k][tx] = 64.0f * W[(size_t)(k0 + k) * F_DIM + f0 + tx];
    }
    __syncthreads();
#pragma unroll
    for (int ff = 0; ff < 4; ++ff) {
      int f = ff * 8 + ty;
      int kk = tx * 4;
      u32 p = pk4_fp8(tile[kk][f], tile[kk + 1][f], tile[kk + 2][f], tile[kk + 3][f]);
      *(u32*)(Wt + (size_t)(f0 + f) * K_IN + k0 + kk) = p;
    }
  } else {                                // ---- prep (single block)
    float s = 0.f;
    for (int i = tid; i < N_ROWS; i += 256) {
      float a = alphas[i];
      beta[i] = a * (float)(2 * ys[i] - 1);
      sq[i] = 0.f;                        // ws is poisoned 0xAA -> must zero
      s += a;
    }
    red[tid] = s;
    __syncthreads();
    for (int off = 128; off; off >>= 1) {
      if (tid < off) red[tid] += red[tid + off];
      __syncthreads();
    }
    if (tid == 0) out[0] = -red[0];
  }
}

// ------- MX-fp8 GEMM core: 128x128 tile, BK=128, 16x16x128 f8f6f4 -------
// LDS rows are 128 B (128 fp8); xor-8 16B-block swizzle (2-way max = free).

template <int K>
__device__ __forceinline__ void gemm_tile_f8(const u8* __restrict__ A, const u8* __restrict__ Bt,
                                             int m0, int n0, u8* sA, u8* sB, int tid,
                                             int sclA, int sclB, f32x4 acc[4][4]) {
  const int lane = tid & 63;
  const int q = lane >> 4;
  const int r = lane & 15;
  const int wave = tid >> 6;
  const int wm = (wave >> 1) << 6;
  const int wn = (wave & 1) << 6;

  const f32x4 zero = {0.f, 0.f, 0.f, 0.f};
#pragma unroll
  for (int mt = 0; mt < 4; ++mt)
#pragma unroll
    for (int nt = 0; nt < 4; ++nt) acc[mt][nt] = zero;

  int rowS[4], colS[4], offS[4];
#pragma unroll
  for (int j = 0; j < 4; ++j) {
    int o = tid * 16 + j * 4096;   // byte offset inside 16KB tile
    int row = o >> 7;              // 128 B per LDS row (128 fp8)
    int cb = (o >> 4) & 7;         // 16B block within row
    rowS[j] = row;
    colS[j] = ((cb ^ (row & 7)) << 4);  // global byte col (xor swizzle)
    offS[j] = o;
  }

  for (int k0 = 0; k0 < K; k0 += 128) {
#pragma unroll
    for (int j = 0; j < 4; ++j) {
      async16(A + (size_t)(m0 + rowS[j]) * K + k0 + colS[j], sA + offS[j]);
      async16(Bt + (size_t)(n0 + rowS[j]) * K + k0 + colS[j], sB + offS[j]);
    }
    __syncthreads();   // drains vmcnt -> staged data visible

    i32x8 af[4], bg[4];
#pragma unroll
    for (int mt = 0; mt < 4; ++mt) {
      int m = wm + (mt << 4) + r;
      i32x4 lo = *(const i32x4*)(sA + m * 128 + ((((q << 1) | 0) ^ (m & 7)) << 4));
      i32x4 hi = *(const i32x4*)(sA + m * 128 + ((((q << 1) | 1) ^ (m & 7)) << 4));
      i32x8 f = {lo[0], lo[1], lo[2], lo[3], hi[0], hi[1], hi[2], hi[3]};
      af[mt] = f;
    }
#pragma unroll
    for (int nt = 0; nt < 4; ++nt) {
      int n = wn + (nt << 4) + r;
      i32x4 lo = *(const i32x4*)(sB + n * 128 + ((((q << 1) | 0) ^ (n & 7)) << 4));
      i32x4 hi = *(const i32x4*)(sB + n * 128 + ((((q << 1) | 1) ^ (n & 7)) << 4));
      i32x8 f = {lo[0], lo[1], lo[2], lo[3], hi[0], hi[1], hi[2], hi[3]};
      bg[nt] = f;
    }
#pragma unroll
    for (int mt = 0; mt < 4; ++mt)
#pragma unroll
      for (int nt = 0; nt < 4; ++nt)
        acc[mt][nt] = __builtin_amdgcn_mfma_scale_f32_16x16x128_f8f6f4(
            af[mt], bg[nt], acc[mt][nt], 0, 0, 0, sclA, 0, sclB);
    __syncthreads();
  }
}

// GEMM1: X = xs_f8 [N_ROWS,K_IN] @ Wt_f8^T -> X_f8 [N_ROWS,F_DIM]
// B-scale = 121 (e8m0 2^-6) undoes the x64 in transpose.
// Fused row-sq epilogue: sq[i] += sum over this block's 128 cols of
// dequant(f8(x))^2 — built from the SAME quantized values stored to X, so
// d2_ii == 0 exactly and K_ii == 1 in gemm_kern.
__global__ __launch_bounds__(256, 3) void gemm_xw(const u8* __restrict__ A,
                                                  const u8* __restrict__ Bt,
                                                  u8* __restrict__ X,
                                                  float* __restrict__ sq) {
  __shared__ __align__(16) u8 sA[128 * 128];
  __shared__ __align__(16) u8 sB[128 * 128];
  const int tid = threadIdx.x;
  const int m0 = blockIdx.y << 7;
  const int n0 = blockIdx.x << 7;
  f32x4 acc[4][4];
  gemm_tile_f8<K_IN>(A, Bt, m0, n0, sA, sB, tid, 127, 121, acc);

  const int lane = tid & 63;
  const int q = lane >> 4;
  const int r = lane & 15;
  const int wave = tid >> 6;
  const int wm = (wave >> 1) << 6;
  const int wn = (wave & 1) << 6;

  float sqs[4][4];   // [mt][e] partial row-sums of x^2 over this thread's cols
#pragma unroll
  for (int mt = 0; mt < 4; ++mt)
#pragma unroll
    for (int e = 0; e < 4; ++e) sqs[mt][e] = 0.f;

#pragma unroll
  for (int mt = 0; mt < 4; ++mt) {
#pragma unroll
    for (int nt = 0; nt < 4; ++nt) {
      int row = m0 + wm + (mt << 4) + (q << 2);
      int col = n0 + wn + (nt << 4) + r;
#pragma unroll
      for (int e = 0; e < 4; ++e) {
        u8 b = f8(acc[mt][nt][e]);
        X[(size_t)(row + e) * F_DIM + col] = b;
        float xd = f8_dec(b);
        sqs[mt][e] += xd * xd;
      }
    }
  }
  // reduce over the 16 lanes of each quad-row (r = lane&15), add to sq
#pragma unroll
  for (int mt = 0; mt < 4; ++mt) {
#pragma unroll
    for (int e = 0; e < 4; ++e) {
      float s = sqs[mt][e];
#pragma unroll
      for (int off = 8; off; off >>= 1) s += __shfl_down(s, off);
      if (r == 0) atomicAdd(&sq[m0 + wm + (mt << 4) + (q << 2) + e], s);
    }
  }
}

// GEMM2 (triangular) + fused RBF epilogue + reduction
__global__ __launch_bounds__(256, 3) void gemm_kern(const u8* __restrict__ X,
                                                    const float* __restrict__ sq,
                                                    const float* __restrict__ beta,
                                                    float* __restrict__ out) {
  __shared__ __align__(16) u8 sA[128 * 128];
  __shared__ __align__(16) u8 sB[128 * 128];
  const int tid = threadIdx.x;
  int bid = blockIdx.x;
  int ib = 0;
  while (bid >= 32 - ib) { bid -= 32 - ib; ++ib; }
  const int jb = ib + bid;
  const int m0 = ib << 7;
  const int n0 = jb << 7;

  f32x4 acc[4][4];
  gemm_tile_f8<F_DIM>(X, X, m0, n0, sA, sB, tid, 127, 127, acc);

  const int lane = tid & 63;
  const int q = lane >> 4;
  const int r = lane & 15;
  const int wave = tid >> 6;
  const int wm = (wave >> 1) << 6;
  const int wn = (wave & 1) << 6;

  float sqj[4], bj[4];
#pragma unroll
  for (int nt = 0; nt < 4; ++nt) {
    int j = n0 + wn + (nt << 4) + r;
    sqj[nt] = sq[j];
    bj[nt] = beta[j];
  }
  float local = 0.f;
#pragma unroll
  for (int mt = 0; mt < 4; ++mt) {
#pragma unroll
    for (int e = 0; e < 4; ++e) {
      int i = m0 + wm + (mt << 4) + (q << 2) + e;
      float sqi = sq[i];
      float bi = beta[i];
#pragma unroll
      for (int nt = 0; nt < 4; ++nt) {
        float d2 = fmaxf(sqi + sqj[nt] - 2.f * acc[mt][nt][e], 0.f);
        local += bi * bj[nt] * __expf(-GAMMA * d2);
      }
    }
  }
  // diag blocks once (x0.5 for the 0.5*quad form), off-diag twice (x1.0)
  local *= (ib == jb) ? 0.5f : 1.0f;
#pragma unroll
  for (int off = 32; off; off >>= 1) local += __shfl_down(local, off);
  if (lane == 0) atomicAdd(out, local);
}

// ---------------- launch ----------------

extern "C" void kernel_launch(void* const* d_in, const int* in_sizes, int n_in,
                              void* d_out, int out_size, void* d_ws, size_t ws_size,
                              hipStream_t stream) {
  const float* xs = (const float*)d_in[0];
  const float* W = (const float*)d_in[1];
  const int* ys = (const int*)d_in[2];
  const float* alphas = (const float*)d_in[3];
  float* out = (float*)d_out;

  char* ws = (char*)d_ws;
  u8* xs_f8 = (u8*)ws;                        //  32 MB: [4096, 8192] fp8
  u8* Wt_f8 = (u8*)(ws + 33554432);           //  16 MB: [2048, 8192] fp8 (x64)
  u8* X_f8  = (u8*)(ws + 50331648);           //   8 MB: [4096, 2048] fp8
  float* sq   = (float*)(ws + 58720256);      //  16 KB
  float* beta = (float*)(ws + 58736640);      //  16 KB

  fused_prep<<<12289, 256, 0, stream>>>((const float4*)xs, (u32*)xs_f8,
                                        W, Wt_f8, alphas, ys, beta, sq, out);

  dim3 g1(F_DIM / 128, N_ROWS / 128);
  gemm_xw<<<g1, 256, 0, stream>>>(xs_f8, Wt_f8, X_f8, sq);
  gemm_kern<<<528, 256, 0, stream>>>(X_f8, sq, beta, out);
}

// Round 6
// 367.737 us; speedup vs baseline: 1.0032x; 1.0032x over previous
//
#include <hip/hip_runtime.h>
#include <hip/hip_bf16.h>

#define N_ROWS 4096
#define K_IN   8192
#define F_DIM  2048
#define GAMMA  (1.0f / 2048.0f)

typedef unsigned short u16;
typedef unsigned int   u32;
typedef unsigned char  u8;
typedef __attribute__((ext_vector_type(4))) int   i32x4;
typedef __attribute__((ext_vector_type(8))) int   i32x8;
typedef __attribute__((ext_vector_type(4))) float f32x4;
typedef __attribute__((ext_vector_type(2))) float f32x2;

__device__ __forceinline__ u32 pk4_fp8(float a, float b, float c, float d) {
  u32 u = 0;
  u = __builtin_amdgcn_cvt_pk_fp8_f32(a, b, u, false);
  u = __builtin_amdgcn_cvt_pk_fp8_f32(c, d, u, true);
  return u;
}
__device__ __forceinline__ u8 f8(float v) {
  return (u8)(__builtin_amdgcn_cvt_pk_fp8_f32(v, v, 0, false) & 0xff);
}
__device__ __forceinline__ float f8_dec(u8 b) {
  f32x2 d = __builtin_amdgcn_cvt_pk_f32_fp8((u32)b, false);
  return d[0];
}

__device__ __forceinline__ void async16(const void* g, void* l) {
  __builtin_amdgcn_global_load_lds(
      (const __attribute__((address_space(1))) void*)g,
      (__attribute__((address_space(3))) void*)l, 16, 0, 0);
}

// ---------------- fused prep v2 ----------------
// bid 0: prep (beta, -sum(alpha), zero sq)
// bids 1..9216, u=bid-1: u%9==8 -> W-transpose unit u/9 (1024 units),
//                        else    -> xs-convert unit (u/9)*8 + u%9 (8192 units)
// Interleaving keeps both HBM streams concurrent across the whole dispatch.
//
// W-unit (64K x 256F tile): coalesced 1KB row reads -> fp8 x64 -> LDS
// (k-major rows of 272B; u32 stores land 2 lanes/bank = free) -> per-thread
// f-column byte gather (4 lanes share one LDS word = broadcast, conflict-free)
// -> 4x dwordx4 stores per f row (64B per thread, L2 merges neighbors).
__global__ __launch_bounds__(256) void fused_prep(
    const float4* __restrict__ xs4, u32* __restrict__ xs_f8,
    const float* __restrict__ W, u8* __restrict__ Wt,
    const float* __restrict__ alphas, const int* __restrict__ ys,
    float* __restrict__ beta, float* __restrict__ sq, float* __restrict__ out) {
  __shared__ __align__(16) u8 smem[64 * 272];   // 17408 B
  const int bid = blockIdx.x;
  const int tid = threadIdx.x;

  if (bid == 0) {                         // ---- prep (single block)
    float* red = (float*)smem;
    float s = 0.f;
    for (int i = tid; i < N_ROWS; i += 256) {
      float a = alphas[i];
      beta[i] = a * (float)(2 * ys[i] - 1);
      sq[i] = 0.f;                        // ws poisoned 0xAA -> must zero
      s += a;
    }
    red[tid] = s;
    __syncthreads();
    for (int off = 128; off; off >>= 1) {
      if (tid < off) red[tid] += red[tid + off];
      __syncthreads();
    }
    if (tid == 0) out[0] = -red[0];
    return;
  }

  const int u = bid - 1;
  const int grp = u / 9;
  const int rem = u - grp * 9;

  if (rem != 8) {                         // ---- xs fp32 -> fp8 (unit scale)
    int x = grp * 8 + rem;                // unit in [0, 8192)
    int base = x * 1024 + tid;
#pragma unroll
    for (int k = 0; k < 4; ++k) {
      int i = base + k * 256;
      float4 v = xs4[i];
      xs_f8[i] = pk4_fp8(v.x, v.y, v.z, v.w);
    }
    return;
  }

  // ---- W [K_IN,F_DIM] fp32 -> Wt [F_DIM,K_IN] fp8 x64 (2^-6 in B-scale)
  const int t = grp;                      // unit in [0, 1024)
  const int k0 = (t & 127) * 64;          // 128 K-chunks
  const int f0 = (t >> 7) * 256;          // 8 F-chunks
  const int w = tid >> 6, l = tid & 63;

  // phase A: coalesced read + convert + LDS store (k-major, 272B rows)
#pragma unroll
  for (int i = 0; i < 16; ++i) {
    int k = w * 16 + i;
    float4 v = *(const float4*)(W + (size_t)(k0 + k) * F_DIM + f0 + 4 * l);
    u32 p = pk4_fp8(64.f * v.x, 64.f * v.y, 64.f * v.z, 64.f * v.w);
    *(u32*)(smem + k * 272 + 4 * l) = p;
  }
  __syncthreads();

  // phase B: per-thread f-column gather -> 64 contiguous K bytes out
  const int f = tid;
  u32 wb[16];
#pragma unroll
  for (int q = 0; q < 16; ++q) {
    const u8* c = smem + (4 * q) * 272 + f;
    wb[q] = (u32)c[0] | ((u32)c[272] << 8) | ((u32)c[544] << 16) | ((u32)c[816] << 24);
  }
  uint4* dst = (uint4*)(Wt + (size_t)(f0 + f) * K_IN + k0);
  dst[0] = make_uint4(wb[0], wb[1], wb[2], wb[3]);
  dst[1] = make_uint4(wb[4], wb[5], wb[6], wb[7]);
  dst[2] = make_uint4(wb[8], wb[9], wb[10], wb[11]);
  dst[3] = make_uint4(wb[12], wb[13], wb[14], wb[15]);
}

// ------- MX-fp8 GEMM core: 128x128 tile, BK=128, 16x16x128 f8f6f4 -------
// LDS rows are 128 B (128 fp8); xor-8 16B-block swizzle (2-way max = free).

template <int K>
__device__ __forceinline__ void gemm_tile_f8(const u8* __restrict__ A, const u8* __restrict__ Bt,
                                             int m0, int n0, u8* sA, u8* sB, int tid,
                                             int sclA, int sclB, f32x4 acc[4][4]) {
  const int lane = tid & 63;
  const int q = lane >> 4;
  const int r = lane & 15;
  const int wave = tid >> 6;
  const int wm = (wave >> 1) << 6;
  const int wn = (wave & 1) << 6;

  const f32x4 zero = {0.f, 0.f, 0.f, 0.f};
#pragma unroll
  for (int mt = 0; mt < 4; ++mt)
#pragma unroll
    for (int nt = 0; nt < 4; ++nt) acc[mt][nt] = zero;

  int rowS[4], colS[4], offS[4];
#pragma unroll
  for (int j = 0; j < 4; ++j) {
    int o = tid * 16 + j * 4096;   // byte offset inside 16KB tile
    int row = o >> 7;              // 128 B per LDS row (128 fp8)
    int cb = (o >> 4) & 7;         // 16B block within row
    rowS[j] = row;
    colS[j] = ((cb ^ (row & 7)) << 4);  // global byte col (xor swizzle)
    offS[j] = o;
  }

  for (int k0 = 0; k0 < K; k0 += 128) {
#pragma unroll
    for (int j = 0; j < 4; ++j) {
      async16(A + (size_t)(m0 + rowS[j]) * K + k0 + colS[j], sA + offS[j]);
      async16(Bt + (size_t)(n0 + rowS[j]) * K + k0 + colS[j], sB + offS[j]);
    }
    __syncthreads();   // drains vmcnt -> staged data visible

    i32x8 af[4], bg[4];
#pragma unroll
    for (int mt = 0; mt < 4; ++mt) {
      int m = wm + (mt << 4) + r;
      i32x4 lo = *(const i32x4*)(sA + m * 128 + ((((q << 1) | 0) ^ (m & 7)) << 4));
      i32x4 hi = *(const i32x4*)(sA + m * 128 + ((((q << 1) | 1) ^ (m & 7)) << 4));
      i32x8 f = {lo[0], lo[1], lo[2], lo[3], hi[0], hi[1], hi[2], hi[3]};
      af[mt] = f;
    }
#pragma unroll
    for (int nt = 0; nt < 4; ++nt) {
      int n = wn + (nt << 4) + r;
      i32x4 lo = *(const i32x4*)(sB + n * 128 + ((((q << 1) | 0) ^ (n & 7)) << 4));
      i32x4 hi = *(const i32x4*)(sB + n * 128 + ((((q << 1) | 1) ^ (n & 7)) << 4));
      i32x8 f = {lo[0], lo[1], lo[2], lo[3], hi[0], hi[1], hi[2], hi[3]};
      bg[nt] = f;
    }
#pragma unroll
    for (int mt = 0; mt < 4; ++mt)
#pragma unroll
      for (int nt = 0; nt < 4; ++nt)
        acc[mt][nt] = __builtin_amdgcn_mfma_scale_f32_16x16x128_f8f6f4(
            af[mt], bg[nt], acc[mt][nt], 0, 0, 0, sclA, 0, sclB);
    __syncthreads();
  }
}

// GEMM1: X = xs_f8 [N_ROWS,K_IN] @ Wt_f8^T -> X_f8 [N_ROWS,F_DIM]
// B-scale = 121 (e8m0 2^-6) undoes the x64 in transpose.
// Fused row-sq epilogue from the SAME stored fp8 -> d2_ii == 0 exact.
__global__ __launch_bounds__(256, 3) void gemm_xw(const u8* __restrict__ A,
                                                  const u8* __restrict__ Bt,
                                                  u8* __restrict__ X,
                                                  float* __restrict__ sq) {
  __shared__ __align__(16) u8 sA[128 * 128];
  __shared__ __align__(16) u8 sB[128 * 128];
  const int tid = threadIdx.x;
  const int m0 = blockIdx.y << 7;
  const int n0 = blockIdx.x << 7;
  f32x4 acc[4][4];
  gemm_tile_f8<K_IN>(A, Bt, m0, n0, sA, sB, tid, 127, 121, acc);

  const int lane = tid & 63;
  const int q = lane >> 4;
  const int r = lane & 15;
  const int wave = tid >> 6;
  const int wm = (wave >> 1) << 6;
  const int wn = (wave & 1) << 6;

  float sqs[4][4];
#pragma unroll
  for (int mt = 0; mt < 4; ++mt)
#pragma unroll
    for (int e = 0; e < 4; ++e) sqs[mt][e] = 0.f;

#pragma unroll
  for (int mt = 0; mt < 4; ++mt) {
#pragma unroll
    for (int nt = 0; nt < 4; ++nt) {
      int row = m0 + wm + (mt << 4) + (q << 2);
      int col = n0 + wn + (nt << 4) + r;
#pragma unroll
      for (int e = 0; e < 4; ++e) {
        u8 b = f8(acc[mt][nt][e]);
        X[(size_t)(row + e) * F_DIM + col] = b;
        float xd = f8_dec(b);
        sqs[mt][e] += xd * xd;
      }
    }
  }
#pragma unroll
  for (int mt = 0; mt < 4; ++mt) {
#pragma unroll
    for (int e = 0; e < 4; ++e) {
      float s = sqs[mt][e];
#pragma unroll
      for (int off = 8; off; off >>= 1) s += __shfl_down(s, off);
      if (r == 0) atomicAdd(&sq[m0 + wm + (mt << 4) + (q << 2) + e], s);
    }
  }
}

// GEMM2 (triangular) + fused RBF epilogue + reduction
__global__ __launch_bounds__(256, 3) void gemm_kern(const u8* __restrict__ X,
                                                    const float* __restrict__ sq,
                                                    const float* __restrict__ beta,
                                                    float* __restrict__ out) {
  __shared__ __align__(16) u8 sA[128 * 128];
  __shared__ __align__(16) u8 sB[128 * 128];
  const int tid = threadIdx.x;
  int bid = blockIdx.x;
  int ib = 0;
  while (bid >= 32 - ib) { bid -= 32 - ib; ++ib; }
  const int jb = ib + bid;
  const int m0 = ib << 7;
  const int n0 = jb << 7;

  f32x4 acc[4][4];
  gemm_tile_f8<F_DIM>(X, X, m0, n0, sA, sB, tid, 127, 127, acc);

  const int lane = tid & 63;
  const int q = lane >> 4;
  const int r = lane & 15;
  const int wave = tid >> 6;
  const int wm = (wave >> 1) << 6;
  const int wn = (wave & 1) << 6;

  float sqj[4], bj[4];
#pragma unroll
  for (int nt = 0; nt < 4; ++nt) {
    int j = n0 + wn + (nt << 4) + r;
    sqj[nt] = sq[j];
    bj[nt] = beta[j];
  }
  float local = 0.f;
#pragma unroll
  for (int mt = 0; mt < 4; ++mt) {
#pragma unroll
    for (int e = 0; e < 4; ++e) {
      int i = m0 + wm + (mt << 4) + (q << 2) + e;
      float sqi = sq[i];
      float bi = beta[i];
#pragma unroll
      for (int nt = 0; nt < 4; ++nt) {
        float d2 = fmaxf(sqi + sqj[nt] - 2.f * acc[mt][nt][e], 0.f);
        local += bi * bj[nt] * __expf(-GAMMA * d2);
      }
    }
  }
  // diag blocks once (x0.5 for the 0.5*quad form), off-diag twice (x1.0)
  local *= (ib == jb) ? 0.5f : 1.0f;
#pragma unroll
  for (int off = 32; off; off >>= 1) local += __shfl_down(local, off);
  if (lane == 0) atomicAdd(out, local);
}

// ---------------- launch ----------------

extern "C" void kernel_launch(void* const* d_in, const int* in_sizes, int n_in,
                              void* d_out, int out_size, void* d_ws, size_t ws_size,
                              hipStream_t stream) {
  const float* xs = (const float*)d_in[0];
  const float* W = (const float*)d_in[1];
  const int* ys = (const int*)d_in[2];
  const float* alphas = (const float*)d_in[3];
  float* out = (float*)d_out;

  char* ws = (char*)d_ws;
  u8* xs_f8 = (u8*)ws;                        //  32 MB: [4096, 8192] fp8
  u8* Wt_f8 = (u8*)(ws + 33554432);           //  16 MB: [2048, 8192] fp8 (x64)
  u8* X_f8  = (u8*)(ws + 50331648);           //   8 MB: [4096, 2048] fp8
  float* sq   = (float*)(ws + 58720256);      //  16 KB
  float* beta = (float*)(ws + 58740736);      //  16 KB

  fused_prep<<<9217, 256, 0, stream>>>((const float4*)xs, (u32*)xs_f8,
                                       W, Wt_f8, alphas, ys, beta, sq, out);

  dim3 g1(F_DIM / 128, N_ROWS / 128);
  gemm_xw<<<g1, 256, 0, stream>>>(xs_f8, Wt_f8, X_f8, sq);
  gemm_kern<<<528, 256, 0, stream>>>(X_f8, sq, beta, out);
}